// Round 1
// baseline (942.466 us; speedup 1.0000x reference)
//
#include <hip/hip_runtime.h>
#include <hip/hip_bf16.h>

// Problem constants
#define Bq 4
#define Nq 2048
#define Mq 2048
#define Dq 1024
#define Hq 16
// HD = 64, scale = 1/8

typedef __attribute__((ext_vector_type(8))) short short8;
typedef __attribute__((ext_vector_type(4))) float floatx4;

static __device__ __forceinline__ short f2bf(float f) {
    __hip_bfloat16 h = __float2bfloat16(f);   // RNE
    short r;
    __builtin_memcpy(&r, &h, 2);
    return r;
}
static __device__ __forceinline__ float bf2f(short s) {
    unsigned u = ((unsigned)(unsigned short)s) << 16;
    float f;
    __builtin_memcpy(&f, &u, 4);
    return f;
}

// ---------------------------------------------------------------------------
// GEMM: C[r][c] = sum_k A[r][k]*B[c][k] + bias[c]
// A: R x K (f32 or bf16), B: 1024 x K f32 ("B^T" layout), C: R x 1024.
// 128x128 tile, 4 waves, BK=32, mfma 16x16x32 bf16. Reg-staged (f32->bf16 cvt),
// XOR-swizzled LDS (unit ^ ((row>>1)&3)) so frag ds_read_b128 is ~conflict-free.
// ---------------------------------------------------------------------------
template<bool A_BF16, bool OUT_BF16>
__global__ __launch_bounds__(256, 2)
void gemm_bt(const void* __restrict__ Ap, const float* __restrict__ Bp,
             const float* __restrict__ biasp, void* __restrict__ Cp, int K)
{
    __shared__ short As[128 * 32];
    __shared__ short Bs[128 * 32];
    short8* As8 = (short8*)As;
    short8* Bs8 = (short8*)Bs;

    const int tid = threadIdx.x;
    const int lane = tid & 63;
    const int wid = tid >> 6;
    const int wr = wid >> 1, wc = wid & 1;
    const int g = lane >> 4, c = lane & 15;
    const long row0 = (long)blockIdx.x * 128;
    const int col0 = blockIdx.y * 128;

    const int srow = tid >> 1;        // 0..127
    const int sk = (tid & 1) * 16;    // 0 / 16

    floatx4 acc[4][4];
#pragma unroll
    for (int i = 0; i < 4; ++i)
#pragma unroll
        for (int j = 0; j < 4; ++j) acc[i][j] = (floatx4)0.0f;

    for (int kt = 0; kt < K; kt += 32) {
        short8 a0, a1, b0, b1;
        if constexpr (A_BF16) {
            const short* ap = (const short*)Ap + (row0 + srow) * (long)K + kt + sk;
            a0 = *(const short8*)ap;
            a1 = *(const short8*)(ap + 8);
        } else {
            const float* ap = (const float*)Ap + (row0 + srow) * (long)K + kt + sk;
            floatx4 f0 = *(const floatx4*)ap,       f1 = *(const floatx4*)(ap + 4),
                    f2 = *(const floatx4*)(ap + 8), f3 = *(const floatx4*)(ap + 12);
#pragma unroll
            for (int e = 0; e < 4; ++e) {
                a0[e] = f2bf(f0[e]); a0[e + 4] = f2bf(f1[e]);
                a1[e] = f2bf(f2[e]); a1[e + 4] = f2bf(f3[e]);
            }
        }
        {
            const float* bp = Bp + (col0 + srow) * (long)K + kt + sk;
            floatx4 f0 = *(const floatx4*)bp,       f1 = *(const floatx4*)(bp + 4),
                    f2 = *(const floatx4*)(bp + 8), f3 = *(const floatx4*)(bp + 12);
#pragma unroll
            for (int e = 0; e < 4; ++e) {
                b0[e] = f2bf(f0[e]); b0[e + 4] = f2bf(f1[e]);
                b1[e] = f2bf(f2[e]); b1[e + 4] = f2bf(f3[e]);
            }
        }
        const int u0 = sk >> 3;            // 16B-unit index within row (0 or 2)
        const int sw = (srow >> 1) & 3;
        As8[srow * 4 + ((u0)     ^ sw)] = a0;
        As8[srow * 4 + ((u0 + 1) ^ sw)] = a1;
        Bs8[srow * 4 + ((u0)     ^ sw)] = b0;
        Bs8[srow * 4 + ((u0 + 1) ^ sw)] = b1;
        __syncthreads();

        short8 af[4], bfq[4];
#pragma unroll
        for (int fm = 0; fm < 4; ++fm) {
            const int r = wr * 64 + fm * 16 + c;   // A-frag row = lane&15
            af[fm] = As8[r * 4 + (g ^ ((r >> 1) & 3))];
        }
#pragma unroll
        for (int fn = 0; fn < 4; ++fn) {
            const int cc = wc * 64 + fn * 16 + c;  // B-frag col = lane&15
            bfq[fn] = Bs8[cc * 4 + (g ^ ((cc >> 1) & 3))];
        }
#pragma unroll
        for (int fm = 0; fm < 4; ++fm)
#pragma unroll
            for (int fn = 0; fn < 4; ++fn)
                acc[fm][fn] = __builtin_amdgcn_mfma_f32_16x16x32_bf16(af[fm], bfq[fn], acc[fm][fn], 0, 0, 0);
        __syncthreads();
    }

    // Epilogue: D layout col = lane&15, row = (lane>>4)*4 + reg  [m89/m91]
#pragma unroll
    for (int fn = 0; fn < 4; ++fn) {
        const int ccol = col0 + wc * 64 + fn * 16 + c;
        const float bv = biasp[ccol];
#pragma unroll
        for (int fm = 0; fm < 4; ++fm) {
            const long r0 = row0 + wr * 64 + fm * 16 + g * 4;
#pragma unroll
            for (int reg = 0; reg < 4; ++reg) {
                const float val = acc[fm][fn][reg] + bv;
                const long idx = (r0 + reg) * 1024 + ccol;
                if constexpr (OUT_BF16) ((short*)Cp)[idx] = f2bf(val);
                else                    ((float*)Cp)[idx] = val;
            }
        }
    }
}

// ---------------------------------------------------------------------------
// Fused flash attention.
// Block: (b, 128-row q-tile, head-group of 4). 8 waves; wave = (head, 64-row half).
// K/V tiles 32x256 bf16 staged in swizzled LDS; bias read direct from global
// (L2-shared, blocks of same (b,qt) pinned to one XCD); online softmax in f32.
// ---------------------------------------------------------------------------
__global__ __launch_bounds__(512, 2)
void attn_fused(const short* __restrict__ qg, const short* __restrict__ kg,
                const short* __restrict__ vg, const float* __restrict__ biasg,
                const int* __restrict__ maskg, short* __restrict__ outg)
{
    __shared__ short k_lds[32 * 256];        // 16 KB
    __shared__ short v_lds[32 * 256];        // 16 KB
    __shared__ short p_lds[8 * 64 * 32];     // 32 KB (per-wave P buffers)
    short8* k8 = (short8*)k_lds;
    short8* v8 = (short8*)v_lds;

    const int tid = threadIdx.x;
    const int lane = tid & 63;
    const int w = tid >> 6;
    const int g = lane >> 4, c = lane & 15;

    // Bijective remap so the 4 head-group blocks of one (b,qt) share an XCD
    // (dispatcher round-robins blockIdx%8 across XCDs) -> bias tile L2 reuse.
    const int L = blockIdx.x;
    const int xcd = L & 7, sIdx = L >> 3;
    const int hg = sIdx & 3;
    const int G = ((sIdx >> 2) << 3) + xcd;  // 0..63 = b*16 + qt
    const int b = G >> 4, qt = G & 15;

    const int h = hg * 4 + (w >> 1);
    const int ih = w & 1;
    const long i0 = (long)qt * 128 + ih * 64;   // query-row base in batch
    const int hoff = (w >> 1) * 64;             // head col offset in staged 256-col group

    // Load q A-frags once, folding in scale=0.125 (exact in bf16).
    short8 aq[4][2];
#pragma unroll
    for (int fm = 0; fm < 4; ++fm)
#pragma unroll
        for (int ks = 0; ks < 2; ++ks) {
            const short* p = qg + ((long)b * Nq + i0 + fm * 16 + c) * Dq + h * 64 + ks * 32 + g * 8;
            short8 t = *(const short8*)p;
#pragma unroll
            for (int e = 0; e < 8; ++e) t[e] = f2bf(bf2f(t[e]) * 0.125f);
            aq[fm][ks] = t;
        }

    float m_s[4][4], l_s[4][4];   // [fm][reg] online-softmax state (rows of this lane's group)
    floatx4 o[4][4];              // O accumulator 64x64 (rows x 4 d-chunks)
#pragma unroll
    for (int fm = 0; fm < 4; ++fm)
#pragma unroll
        for (int r = 0; r < 4; ++r) { m_s[fm][r] = -1e30f; l_s[fm][r] = 0.0f; }
#pragma unroll
    for (int fm = 0; fm < 4; ++fm)
#pragma unroll
        for (int fn = 0; fn < 4; ++fn) o[fm][fn] = (floatx4)0.0f;

    const int srow = tid >> 4;   // staging row 0..31
    const int su = tid & 15;     // staging unit-pair

    for (int kt = 0; kt < 64; ++kt) {
        const int j0 = kt * 32;
        {   // stage k & v tiles (32 rows x 256 cols bf16), unit-swizzled by (row&15)
            const long gro = ((long)b * Mq + j0 + srow) * Dq + hg * 256 + su * 16;
            const short8* kp = (const short8*)(kg + gro);
            const short8* vp = (const short8*)(vg + gro);
            short8 k0 = kp[0], k1 = kp[1], v0 = vp[0], v1 = vp[1];
            const int swz = srow & 15;
            k8[srow * 32 + ((su * 2)     ^ swz)] = k0;
            k8[srow * 32 + ((su * 2 + 1) ^ swz)] = k1;
            v8[srow * 32 + ((su * 2)     ^ swz)] = v0;
            v8[srow * 32 + ((su * 2 + 1) ^ swz)] = v1;
        }
        __syncthreads();

        // --- QK^T: S (64 q x 32 k) for this wave's head ---
        floatx4 sAcc[4][2];
#pragma unroll
        for (int fm = 0; fm < 4; ++fm)
#pragma unroll
            for (int fn = 0; fn < 2; ++fn) sAcc[fm][fn] = (floatx4)0.0f;
        short8 bk[2][2];
#pragma unroll
        for (int fn = 0; fn < 2; ++fn) {
            const int j = fn * 16 + c;           // B-frag col = key index
#pragma unroll
            for (int ks = 0; ks < 2; ++ks) {
                const int u = (hoff >> 3) + ks * 4 + g;
                bk[fn][ks] = k8[j * 32 + (u ^ (j & 15))];
            }
        }
#pragma unroll
        for (int fm = 0; fm < 4; ++fm)
#pragma unroll
            for (int fn = 0; fn < 2; ++fn)
#pragma unroll
                for (int ks = 0; ks < 2; ++ks)
                    sAcc[fm][fn] = __builtin_amdgcn_mfma_f32_16x16x32_bf16(aq[fm][ks], bk[fn][ks], sAcc[fm][fn], 0, 0, 0);

        // --- bias + mask + online softmax, write P (bf16) to private LDS ---
        const float bm0 = maskg[b * Mq + j0 + c]      ? -1e30f : 0.0f;
        const float bm1 = maskg[b * Mq + j0 + 16 + c] ? -1e30f : 0.0f;
        short* pw = p_lds + w * 2048;
#pragma unroll
        for (int fm = 0; fm < 4; ++fm) {
#pragma unroll
            for (int reg = 0; reg < 4; ++reg) {
                const long irow = i0 + fm * 16 + g * 4 + reg;
                const float* bp = biasg + ((long)b * Nq + irow) * Mq + j0;
                float t0 = sAcc[fm][0][reg] + bp[c] + bm0;
                float t1 = sAcc[fm][1][reg] + bp[16 + c] + bm1;
                float pm = fmaxf(t0, t1);
                pm = fmaxf(pm, __shfl_xor(pm, 1));
                pm = fmaxf(pm, __shfl_xor(pm, 2));
                pm = fmaxf(pm, __shfl_xor(pm, 4));
                pm = fmaxf(pm, __shfl_xor(pm, 8));
                const float mold = m_s[fm][reg];
                const float mnew = fmaxf(mold, pm);
                const float alpha = __expf(mold - mnew);
                const float p0 = __expf(t0 - mnew);
                const float p1 = __expf(t1 - mnew);
                float rs = p0 + p1;
                rs += __shfl_xor(rs, 1);
                rs += __shfl_xor(rs, 2);
                rs += __shfl_xor(rs, 4);
                rs += __shfl_xor(rs, 8);
                l_s[fm][reg] = l_s[fm][reg] * alpha + rs;
                m_s[fm][reg] = mnew;
#pragma unroll
                for (int fn = 0; fn < 4; ++fn) o[fm][fn][reg] *= alpha;
                const int il = fm * 16 + g * 4 + reg;
                const int sw3 = ((il >> 1) & 3) << 3;
                pw[il * 32 + ((c)      ^ sw3)] = f2bf(p0);
                pw[il * 32 + ((16 + c) ^ sw3)] = f2bf(p1);
            }
        }

        // --- PV: O += P (64x32) * V (32x64) ---
        short8 ap[4];
#pragma unroll
        for (int fm = 0; fm < 4; ++fm) {
            const int il = fm * 16 + c;          // A-frag row
            ap[fm] = *(const short8*)(pw + il * 32 + ((g ^ ((il >> 1) & 3)) << 3));
        }
        short8 bv[4];
#pragma unroll
        for (int fn = 0; fn < 4; ++fn) {
#pragma unroll
            for (int e = 0; e < 8; ++e) {
                const int j = g * 8 + e;                 // K index (key)
                const int d = hoff + fn * 16 + c;        // col (d)
                bv[fn][e] = v_lds[j * 256 + (d ^ ((j & 15) << 3))];
            }
        }
#pragma unroll
        for (int fm = 0; fm < 4; ++fm)
#pragma unroll
            for (int fn = 0; fn < 4; ++fn)
                o[fm][fn] = __builtin_amdgcn_mfma_f32_16x16x32_bf16(ap[fm], bv[fn], o[fm][fn], 0, 0, 0);
        __syncthreads();
    }

    // finalize: divide by l, store bf16 (B,N,D) with heads concatenated
#pragma unroll
    for (int fm = 0; fm < 4; ++fm)
#pragma unroll
        for (int reg = 0; reg < 4; ++reg) {
            const long irow = i0 + fm * 16 + g * 4 + reg;
            const float invl = 1.0f / l_s[fm][reg];
            short* op = outg + ((long)b * Nq + irow) * Dq + h * 64;
#pragma unroll
            for (int fn = 0; fn < 4; ++fn)
                op[fn * 16 + c] = f2bf(o[fm][fn][reg] * invl);
        }
}

// ---------------------------------------------------------------------------
extern "C" void kernel_launch(void* const* d_in, const int* in_sizes, int n_in,
                              void* d_out, int out_size, void* d_ws, size_t ws_size,
                              hipStream_t stream)
{
    const float* Q    = (const float*)d_in[0];
    const float* K    = (const float*)d_in[1];
    const float* V    = (const float*)d_in[2];
    const float* bias = (const float*)d_in[3];
    const int*   mask = (const int*)d_in[4];
    const float* Wq   = (const float*)d_in[5];
    const float* bq   = (const float*)d_in[6];
    const float* Wk   = (const float*)d_in[7];
    const float* bk   = (const float*)d_in[8];
    const float* Wv   = (const float*)d_in[9];
    const float* bv   = (const float*)d_in[10];
    const float* Wo   = (const float*)d_in[11];
    const float* bo   = (const float*)d_in[12];

    // ws layout: q | k | v | attn_out, all bf16 (B*2048*1024 each) = 67 MB total
    short* q_ws = (short*)d_ws;
    short* k_ws = q_ws + (size_t)Bq * Nq * Dq;
    short* v_ws = k_ws + (size_t)Bq * Mq * Dq;
    short* a_ws = v_ws + (size_t)Bq * Mq * Dq;

    dim3 grid(64, 8);   // 8192 rows x 1024 cols in 128x128 tiles
    gemm_bt<false, true><<<grid, 256, 0, stream>>>(Q, Wq, bq, q_ws, Dq);
    gemm_bt<false, true><<<grid, 256, 0, stream>>>(K, Wk, bk, k_ws, Dq);
    gemm_bt<false, true><<<grid, 256, 0, stream>>>(V, Wv, bv, v_ws, Dq);
    attn_fused<<<dim3(256), dim3(512), 0, stream>>>(q_ws, k_ws, v_ws, bias, mask, a_ws);
    gemm_bt<true, false><<<grid, 256, 0, stream>>>(a_ws, Wo, bo, d_out, Dq);
}

// Round 2
// 359.409 us; speedup vs baseline: 2.6223x; 2.6223x over previous
//
#include <hip/hip_runtime.h>
#include <hip/hip_bf16.h>

// Problem constants
#define Bq 4
#define Nq 2048
#define Mq 2048
#define Dq 1024
#define Hq 16
// HD = 64, scale = 1/8 (folded into Q-projection GEMM)

typedef __attribute__((ext_vector_type(8))) short short8;
typedef __attribute__((ext_vector_type(4))) short short4v;
typedef __attribute__((ext_vector_type(4))) float floatx4;
typedef __attribute__((ext_vector_type(16))) float floatx16;
typedef __attribute__((ext_vector_type(4))) unsigned uint4v;

static __device__ __forceinline__ short f2bf(float f) {
    __hip_bfloat16 h = __float2bfloat16(f);   // RNE
    short r;
    __builtin_memcpy(&r, &h, 2);
    return r;
}
static __device__ __forceinline__ float bf2f(short s) {
    unsigned u = ((unsigned)(unsigned short)s) << 16;
    float f;
    __builtin_memcpy(&f, &u, 4);
    return f;
}
static __device__ __forceinline__ unsigned cvtpk_bf16(float lo, float hi) {
    unsigned r;
    asm("v_cvt_pk_bf16_f32 %0, %1, %2" : "=v"(r) : "v"(lo), "v"(hi));
    return r;
}
// v_permlane32_swap_b32 a,b : a'[32..63]=b[0..31], b'[0..31]=a[32..63]
static __device__ __forceinline__ void swap32(unsigned &a, unsigned &b) {
    asm("v_permlane32_swap_b32 %0, %1" : "+v"(a), "+v"(b));
}
static __device__ __forceinline__ void gld16(const void* g, void* l) {
    __builtin_amdgcn_global_load_lds(
        (const __attribute__((address_space(1))) unsigned int*)g,
        (__attribute__((address_space(3))) unsigned int*)l, 16, 0, 0);
}

// ---------------------------------------------------------------------------
// bias prepass: bm[b][n][m] = bf16(bias + (mask[b][m] ? -1e38 : 0))
// ---------------------------------------------------------------------------
__global__ void bias_prep(const float* __restrict__ bias, const int* __restrict__ mask,
                          short* __restrict__ out)
{
    const long i = ((long)blockIdx.x * 256 + threadIdx.x) * 4;
    const int m = (int)(i & (Mq - 1));
    const int b = (int)(i >> 22);           // i / (2048*2048)
    floatx4 v = *(const floatx4*)(bias + i);
    short4v o;
#pragma unroll
    for (int e = 0; e < 4; ++e) {
        const float t = v[e] + (mask[b * Mq + m + e] ? -1e38f : 0.0f);
        o[e] = f2bf(t);
    }
    *(short4v*)(out + i) = o;
}

// ---------------------------------------------------------------------------
// GEMM: C[r][c] = (sum_k A[r][k]*B[c][k] + bias[c]) * scale
// OMODE: 0 = f32 normal [r][c], 1 = bf16 normal, 2 = bf16 transposed-per-batch
//        ([b][c][m] with r = b*2048+m)  -- used to produce V^T for attention.
// ---------------------------------------------------------------------------
template<bool A_BF16, int OMODE>
__global__ __launch_bounds__(256, 2)
void gemm_bt(const void* __restrict__ Ap, const float* __restrict__ Bp,
             const float* __restrict__ biasp, void* __restrict__ Cp, int K, float scale)
{
    __shared__ short As[128 * 32];
    __shared__ short Bs[128 * 32];
    short8* As8 = (short8*)As;
    short8* Bs8 = (short8*)Bs;

    const int tid = threadIdx.x;
    const int lane = tid & 63;
    const int wid = tid >> 6;
    const int wr = wid >> 1, wc = wid & 1;
    const int g = lane >> 4, c = lane & 15;
    const long row0 = (long)blockIdx.x * 128;
    const int col0 = blockIdx.y * 128;

    const int srow = tid >> 1;        // 0..127
    const int sk = (tid & 1) * 16;    // 0 / 16

    floatx4 acc[4][4];
#pragma unroll
    for (int i = 0; i < 4; ++i)
#pragma unroll
        for (int j = 0; j < 4; ++j) acc[i][j] = (floatx4)0.0f;

    for (int kt = 0; kt < K; kt += 32) {
        short8 a0, a1, b0, b1;
        if constexpr (A_BF16) {
            const short* ap = (const short*)Ap + (row0 + srow) * (long)K + kt + sk;
            a0 = *(const short8*)ap;
            a1 = *(const short8*)(ap + 8);
        } else {
            const float* ap = (const float*)Ap + (row0 + srow) * (long)K + kt + sk;
            floatx4 f0 = *(const floatx4*)ap,       f1 = *(const floatx4*)(ap + 4),
                    f2 = *(const floatx4*)(ap + 8), f3 = *(const floatx4*)(ap + 12);
#pragma unroll
            for (int e = 0; e < 4; ++e) {
                a0[e] = f2bf(f0[e]); a0[e + 4] = f2bf(f1[e]);
                a1[e] = f2bf(f2[e]); a1[e + 4] = f2bf(f3[e]);
            }
        }
        {
            const float* bp = Bp + (col0 + srow) * (long)K + kt + sk;
            floatx4 f0 = *(const floatx4*)bp,       f1 = *(const floatx4*)(bp + 4),
                    f2 = *(const floatx4*)(bp + 8), f3 = *(const floatx4*)(bp + 12);
#pragma unroll
            for (int e = 0; e < 4; ++e) {
                b0[e] = f2bf(f0[e]); b0[e + 4] = f2bf(f1[e]);
                b1[e] = f2bf(f2[e]); b1[e + 4] = f2bf(f3[e]);
            }
        }
        const int u0 = sk >> 3;
        const int sw = (srow >> 1) & 3;
        As8[srow * 4 + ((u0)     ^ sw)] = a0;
        As8[srow * 4 + ((u0 + 1) ^ sw)] = a1;
        Bs8[srow * 4 + ((u0)     ^ sw)] = b0;
        Bs8[srow * 4 + ((u0 + 1) ^ sw)] = b1;
        __syncthreads();

        short8 af[4], bfq[4];
#pragma unroll
        for (int fm = 0; fm < 4; ++fm) {
            const int r = wr * 64 + fm * 16 + c;
            af[fm] = As8[r * 4 + (g ^ ((r >> 1) & 3))];
        }
#pragma unroll
        for (int fn = 0; fn < 4; ++fn) {
            const int cc = wc * 64 + fn * 16 + c;
            bfq[fn] = Bs8[cc * 4 + (g ^ ((cc >> 1) & 3))];
        }
#pragma unroll
        for (int fm = 0; fm < 4; ++fm)
#pragma unroll
            for (int fn = 0; fn < 4; ++fn)
                acc[fm][fn] = __builtin_amdgcn_mfma_f32_16x16x32_bf16(af[fm], bfq[fn], acc[fm][fn], 0, 0, 0);
        __syncthreads();
    }

#pragma unroll
    for (int fn = 0; fn < 4; ++fn) {
        const int ccol = col0 + wc * 64 + fn * 16 + c;
        const float bv = biasp[ccol];
#pragma unroll
        for (int fm = 0; fm < 4; ++fm) {
            const long r0 = row0 + wr * 64 + fm * 16 + g * 4;
#pragma unroll
            for (int reg = 0; reg < 4; ++reg) {
                const float val = (acc[fm][fn][reg] + bv) * scale;
                const long rr = r0 + reg;
                if constexpr (OMODE == 0) {
                    ((float*)Cp)[rr * 1024 + ccol] = val;
                } else if constexpr (OMODE == 1) {
                    ((short*)Cp)[rr * 1024 + ccol] = f2bf(val);
                } else {
                    // V^T per batch: [b][c][m]
                    const long idx = ((long)(rr >> 11) * Dq + ccol) * (long)Mq + (rr & (Mq - 1));
                    ((short*)Cp)[idx] = f2bf(val);
                }
            }
        }
    }
}

// ---------------------------------------------------------------------------
// Fused flash attention, swapped-operand 32x32 structure.
// Grid: 256 blocks = (b,qt,h) remapped XCD-chunked; 8 waves x 512 threads.
// Wave: 64 q-rows (2 q-groups of 32, q = lane&31). KVBLK=64.
// QK^T: mfma(A=K, B=Q) -> S[key][q] (q lane-local).
// PV:   mfma(A=V^T, B=P) -> O^T[d][q] (q lane-local; rescale is scalar).
// K / V^T staged via global_load_lds w=16 with pre-swizzled source (u ^= row&7).
// ---------------------------------------------------------------------------
__global__ __launch_bounds__(512, 2)
void attn_fused(const short* __restrict__ qg_, const short* __restrict__ kg_,
                const short* __restrict__ vtg, const short* __restrict__ bmg,
                short* __restrict__ outg)
{
    __shared__ __align__(16) short k_lds[64 * 64];   // [key r][unit u'] 8KB
    __shared__ __align__(16) short v_lds[64 * 64];   // [d row][key-unit u'] 8KB

    const int tid = threadIdx.x;
    const int lane = tid & 63;
    const int w = tid >> 6;
    const int hi = lane >> 5;
    const int q31 = lane & 31;

    // XCD-chunked remap: each XCD gets 2 (b,qt) groups x 16 heads -> the 16
    // blocks sharing one 2MB bias tile co-reside on one XCD's L2.
    const int blk = blockIdx.x;
    const int xcd = blk & 7, s = blk >> 3;
    const int grp = xcd * 2 + (s >> 4);     // 0..15 = b*4 + qt
    const int b = grp >> 2, qt = grp & 3;
    const int h = s & 15;

    const long qbase = (long)b * Nq + qt * 512 + w * 64;   // + qg*32 + q31

    // Q B-frags (scale already folded in by the projection GEMM)
    short8 qf[2][4];
#pragma unroll
    for (int qg = 0; qg < 2; ++qg)
#pragma unroll
        for (int ks = 0; ks < 4; ++ks)
            qf[qg][ks] = *(const short8*)(qg_ + (qbase + qg * 32 + q31) * Dq + h * 64 + ks * 16 + hi * 8);

    floatx16 oa[2][2];
    float m_s[2], l_s[2];
#pragma unroll
    for (int qg = 0; qg < 2; ++qg) {
        m_s[qg] = -1e37f; l_s[qg] = 0.0f;
        oa[qg][0] = (floatx16)0.0f; oa[qg][1] = (floatx16)0.0f;
    }

    // staging: thread = LDS unit U = tid; row r = U>>3, stored unit u' = U&7,
    // source unit u = u' ^ (r&7)  (inverse-swizzled global source, linear LDS)
    const int sr = tid >> 3;
    const int su = (tid & 7) ^ (sr & 7);
    const char* ksrc0 = (const char*)(kg_ + ((long)b * Mq + sr) * Dq + h * 64 + su * 8);
    const char* vsrc0 = (const char*)(vtg + ((long)b * Dq + h * 64 + sr) * Mq + su * 8);
    void* kdst = (void*)((char*)k_lds + w * 1024);
    void* vdst = (void*)((char*)v_lds + w * 1024);

    for (int kt = 0; kt < 32; ++kt) {
        const long j0 = (long)kt * 64;
        gld16(ksrc0 + j0 * (Dq * 2), kdst);   // advance by j0 key-rows
        gld16(vsrc0 + j0 * 2, vdst);          // advance by j0 key-cols
        __syncthreads();

        // K A-frags + QK^T
        short8 kf[2][4];
#pragma unroll
        for (int kg = 0; kg < 2; ++kg)
#pragma unroll
            for (int ks = 0; ks < 4; ++ks) {
                const int r = kg * 32 + q31;
                const int up = (2 * ks + hi) ^ (r & 7);
                kf[kg][ks] = *(const short8*)((const char*)k_lds + r * 128 + up * 16);
            }
        floatx16 sa[2][2];
#pragma unroll
        for (int qg = 0; qg < 2; ++qg)
#pragma unroll
            for (int kg = 0; kg < 2; ++kg) {
                sa[qg][kg] = (floatx16)0.0f;
#pragma unroll
                for (int ks = 0; ks < 4; ++ks)
                    sa[qg][kg] = __builtin_amdgcn_mfma_f32_32x32x16_bf16(kf[kg][ks], qf[qg][ks], sa[qg][kg], 0, 0, 0);
            }

        // V^T A-frags
        short8 vf[2][4];
#pragma unroll
        for (int dg = 0; dg < 2; ++dg)
#pragma unroll
            for (int ks = 0; ks < 4; ++ks) {
                const int r = dg * 32 + q31;
                const int up = (2 * ks + hi) ^ (r & 7);
                vf[dg][ks] = *(const short8*)((const char*)v_lds + r * 128 + up * 16);
            }

#pragma unroll
        for (int qg = 0; qg < 2; ++qg) {
            // logits: S reg r of key-group kg = key crow(r,hi)=(r&3)+8*(r>>2)+4hi (+32kg)
            const short* brow = bmg + (qbase + qg * 32 + q31) * Mq + j0;
            float p[32];
#pragma unroll
            for (int kg = 0; kg < 2; ++kg)
#pragma unroll
                for (int Qh = 0; Qh < 4; ++Qh) {
                    short4v bb = *(const short4v*)(brow + kg * 32 + Qh * 8 + hi * 4);
#pragma unroll
                    for (int e = 0; e < 4; ++e)
                        p[kg * 16 + Qh * 4 + e] = sa[qg][kg][Qh * 4 + e] + bf2f(bb[e]);
                }
            // row max: in-lane tree + cross-half
            float pm = p[0];
#pragma unroll
            for (int i = 1; i < 32; ++i) pm = fmaxf(pm, p[i]);
            pm = fmaxf(pm, __shfl_xor(pm, 32));
            // defer-max rescale (THR=8)
            if (!__all(pm <= m_s[qg] + 8.0f)) {
                const float mn = fmaxf(m_s[qg], pm);
                const float al = __expf(m_s[qg] - mn);
                l_s[qg] *= al;
                oa[qg][0] *= al; oa[qg][1] *= al;
                m_s[qg] = mn;
            }
            float rs = 0.0f;
#pragma unroll
            for (int i = 0; i < 32; ++i) { p[i] = __expf(p[i] - m_s[qg]); rs += p[i]; }
            rs += __shfl_xor(rs, 32);
            l_s[qg] += rs;

            // pack P -> PV B-frags via cvt_pk + permlane32_swap (T12)
            uint4v pw[4];
#pragma unroll
            for (int kg = 0; kg < 2; ++kg) {
                unsigned w0 = cvtpk_bf16(p[kg * 16 + 0], p[kg * 16 + 1]);
                unsigned w1 = cvtpk_bf16(p[kg * 16 + 2], p[kg * 16 + 3]);
                unsigned w2 = cvtpk_bf16(p[kg * 16 + 4], p[kg * 16 + 5]);
                unsigned w3 = cvtpk_bf16(p[kg * 16 + 6], p[kg * 16 + 7]);
                swap32(w0, w2); swap32(w1, w3);
                pw[kg * 2][0] = w0; pw[kg * 2][1] = w1; pw[kg * 2][2] = w2; pw[kg * 2][3] = w3;
                unsigned w4 = cvtpk_bf16(p[kg * 16 + 8],  p[kg * 16 + 9]);
                unsigned w5 = cvtpk_bf16(p[kg * 16 + 10], p[kg * 16 + 11]);
                unsigned w6 = cvtpk_bf16(p[kg * 16 + 12], p[kg * 16 + 13]);
                unsigned w7 = cvtpk_bf16(p[kg * 16 + 14], p[kg * 16 + 15]);
                swap32(w4, w6); swap32(w5, w7);
                pw[kg * 2 + 1][0] = w4; pw[kg * 2 + 1][1] = w5; pw[kg * 2 + 1][2] = w6; pw[kg * 2 + 1][3] = w7;
            }
#pragma unroll
            for (int dg = 0; dg < 2; ++dg)
#pragma unroll
                for (int ks = 0; ks < 4; ++ks)
                    oa[qg][dg] = __builtin_amdgcn_mfma_f32_32x32x16_bf16(
                        vf[dg][ks], __builtin_bit_cast(short8, pw[ks]), oa[qg][dg], 0, 0, 0);
        }
        __syncthreads();
    }

    // epilogue: O^T reg r (+32dg) = d = (r&3)+8*(r>>2)+4hi+32dg, q = lane&31
#pragma unroll
    for (int qg = 0; qg < 2; ++qg) {
        const float invl = 1.0f / l_s[qg];
        short* op = outg + (qbase + qg * 32 + q31) * Dq + h * 64;
#pragma unroll
        for (int dg = 0; dg < 2; ++dg)
#pragma unroll
            for (int Qh = 0; Qh < 4; ++Qh) {
                short4v t;
#pragma unroll
                for (int e = 0; e < 4; ++e)
                    t[e] = f2bf(oa[qg][dg][Qh * 4 + e] * invl);
                *(short4v*)(op + dg * 32 + Qh * 8 + hi * 4) = t;
            }
    }
}

// ---------------------------------------------------------------------------
extern "C" void kernel_launch(void* const* d_in, const int* in_sizes, int n_in,
                              void* d_out, int out_size, void* d_ws, size_t ws_size,
                              hipStream_t stream)
{
    const float* Q    = (const float*)d_in[0];
    const float* K    = (const float*)d_in[1];
    const float* V    = (const float*)d_in[2];
    const float* bias = (const float*)d_in[3];
    const int*   mask = (const int*)d_in[4];
    const float* Wq   = (const float*)d_in[5];
    const float* bq   = (const float*)d_in[6];
    const float* Wk   = (const float*)d_in[7];
    const float* bk   = (const float*)d_in[8];
    const float* Wv   = (const float*)d_in[9];
    const float* bv   = (const float*)d_in[10];
    const float* Wo   = (const float*)d_in[11];
    const float* bo   = (const float*)d_in[12];

    // ws: q | k | vT | attn_out | bias_masked  (bf16, 33.5MB each = 168MB)
    const size_t SZ = (size_t)Bq * Nq * Dq;       // 8.4M elems (also B*N*M/2 slots: bias uses B*N*M)
    short* q_ws  = (short*)d_ws;
    short* k_ws  = q_ws  + (size_t)Bq * Nq * Dq;
    short* vt_ws = k_ws  + (size_t)Bq * Mq * Dq;
    short* a_ws  = vt_ws + (size_t)Bq * Mq * Dq;
    short* bm_ws = a_ws  + (size_t)Bq * Nq * Dq;
    (void)SZ; (void)ws_size;

    bias_prep<<<dim3((Bq * Nq * Mq) / 4 / 256), dim3(256), 0, stream>>>(bias, mask, bm_ws);

    dim3 grid(64, 8);
    gemm_bt<false, 1><<<grid, 256, 0, stream>>>(Q, Wq, bq, q_ws, Dq, 0.125f);
    gemm_bt<false, 1><<<grid, 256, 0, stream>>>(K, Wk, bk, k_ws, Dq, 1.0f);
    gemm_bt<false, 2><<<grid, 256, 0, stream>>>(V, Wv, bv, vt_ws, Dq, 1.0f);
    attn_fused<<<dim3(256), dim3(512), 0, stream>>>(q_ws, k_ws, vt_ws, bm_ws, a_ws);
    gemm_bt<true, 0><<<grid, 256, 0, stream>>>(a_ws, Wo, bo, d_out, Dq, 1.0f);
}

// Round 3
// 342.352 us; speedup vs baseline: 2.7529x; 1.0498x over previous
//
#include <hip/hip_runtime.h>
#include <hip/hip_bf16.h>

// Problem constants
#define Bq 4
#define Nq 2048
#define Mq 2048
#define Dq 1024
#define Hq 16
// HD = 64; logits computed in exp2 domain: scale 0.125*log2e folded into Q GEMM,
// log2e folded into bias prepass.

typedef __attribute__((ext_vector_type(8))) short short8;
typedef __attribute__((ext_vector_type(4))) short short4v;
typedef __attribute__((ext_vector_type(4))) float floatx4;
typedef __attribute__((ext_vector_type(16))) float floatx16;
typedef __attribute__((ext_vector_type(4))) unsigned uint4v;

static __device__ __forceinline__ short f2bf(float f) {
    __hip_bfloat16 h = __float2bfloat16(f);   // RNE
    short r;
    __builtin_memcpy(&r, &h, 2);
    return r;
}
static __device__ __forceinline__ float bf2f(short s) {
    unsigned u = ((unsigned)(unsigned short)s) << 16;
    float f;
    __builtin_memcpy(&f, &u, 4);
    return f;
}
static __device__ __forceinline__ unsigned cvtpk_bf16(float lo, float hi) {
    unsigned r;
    asm("v_cvt_pk_bf16_f32 %0, %1, %2" : "=v"(r) : "v"(lo), "v"(hi));
    return r;
}
static __device__ __forceinline__ void swap32(unsigned &a, unsigned &b) {
    asm("v_permlane32_swap_b32 %0, %1" : "+v"(a), "+v"(b));
}
static __device__ __forceinline__ float exp2_fast(float x) {
    float r;
    asm("v_exp_f32 %0, %1" : "=v"(r) : "v"(x));   // D = 2^S0
    return r;
}
static __device__ __forceinline__ void gld16(const void* g, void* l) {
    __builtin_amdgcn_global_load_lds(
        (const __attribute__((address_space(1))) unsigned int*)g,
        (__attribute__((address_space(3))) unsigned int*)l, 16, 0, 0);
}

// ---------------------------------------------------------------------------
// bias prepass: bm[b][n][m] = bf16(mask ? -1e38 : bias*log2e)
// ---------------------------------------------------------------------------
__global__ void bias_prep(const float* __restrict__ bias, const int* __restrict__ mask,
                          short* __restrict__ out)
{
    const long i = ((long)blockIdx.x * 256 + threadIdx.x) * 8;
    const int m = (int)(i & (Mq - 1));
    const int b = (int)(i >> 22);           // i / (2048*2048)
    floatx4 f0 = *(const floatx4*)(bias + i);
    floatx4 f1 = *(const floatx4*)(bias + i + 4);
    const int* mp = mask + b * Mq + m;
    short8 o;
#pragma unroll
    for (int e = 0; e < 4; ++e) {
        o[e]     = mp[e]     ? f2bf(-1e38f) : f2bf(f0[e] * 1.44269504f);
        o[e + 4] = mp[e + 4] ? f2bf(-1e38f) : f2bf(f1[e] * 1.44269504f);
    }
    *(short8*)(out + i) = o;
}

// ---------------------------------------------------------------------------
// weight f32 -> bf16 (4 x 1024x1024, z selects)
// ---------------------------------------------------------------------------
__global__ void cvt_w(const float* __restrict__ w0, const float* __restrict__ w1,
                      const float* __restrict__ w2, const float* __restrict__ w3,
                      short* __restrict__ out)
{
    const int z = blockIdx.y;
    const float* s = (z == 0) ? w0 : (z == 1) ? w1 : (z == 2) ? w2 : w3;
    short* d = out + (size_t)z * (Dq * Dq);
    const int i = (blockIdx.x * 256 + threadIdx.x) * 8;
    floatx4 f0 = *(const floatx4*)(s + i);
    floatx4 f1 = *(const floatx4*)(s + i + 4);
    short8 o;
#pragma unroll
    for (int e = 0; e < 4; ++e) { o[e] = f2bf(f0[e]); o[e + 4] = f2bf(f1[e]); }
    *(short8*)(d + i) = o;
}

// ---------------------------------------------------------------------------
// Batched GEMM: C[r][c] = (sum_k A[r][k]*W[c][k] + bias[c]) * scale
// A: 8192 x K (f32 if !ABF, bf16 if ABF), W: 1024 x K bf16.
// 128x128 tile, 4 waves, BK=32, double-buffered LDS, single barrier per K-step.
// B staged via global_load_lds w=16 with pre-swizzled source; A reg-staged
// (issue loads early, cvt+ds_write after MFMA). omode: 0 bf16 [r][c],
// 1 bf16 transposed-per-batch ([b][c][m]), 2 f32 [r][c].
// ---------------------------------------------------------------------------
struct GB {
    const void* A[3];
    const short* W[3];
    const float* bias[3];
    void* C[3];
    float scale[3];
    int omode[3];
};

template<bool ABF>
__global__ __launch_bounds__(256, 3)
void gemm_bt(GB gb, int K)
{
    __shared__ __align__(16) short As[2][128 * 32];
    __shared__ __align__(16) short Bs[2][128 * 32];

    const int z = blockIdx.z;
    const char* Ap = (const char*)gb.A[z];
    const short* Wp = gb.W[z];

    const int tid = threadIdx.x;
    const int lane = tid & 63;
    const int wid = tid >> 6;
    const int wr = wid >> 1, wc = wid & 1;
    const int g = lane >> 4, c = lane & 15;
    const long row0 = (long)blockIdx.x * 128;
    const int col0 = blockIdx.y * 128;

    // A reg-staging coords
    const int srow = tid >> 1;        // 0..127
    const int sk = (tid & 1) * 16;    // 0 / 16
    // B gld-staging coords: issue i covers rows i*64 + (tid>>2); unit swizzle
    const int R0 = tid >> 2;                       // 0..63
    const int ub = (tid & 3) ^ ((R0 >> 1) & 3);    // same for both issues
    const short* bsrc = Wp + ((long)col0 + R0) * K + ub * 8;

    floatx4 acc[4][4];
#pragma unroll
    for (int i = 0; i < 4; ++i)
#pragma unroll
        for (int j = 0; j < 4; ++j) acc[i][j] = (floatx4)0.0f;

    // ---- prologue: stage tile 0 into buf 0 ----
    {
        char* d0 = (char*)Bs + wid * 1024;
        gld16(bsrc, d0);
        gld16(bsrc + 64L * K, d0 + 4096);
    }
    {
        short8 a0, a1;
        if constexpr (ABF) {
            const short* ap = (const short*)Ap + (row0 + srow) * (long)K + sk;
            a0 = *(const short8*)ap; a1 = *(const short8*)(ap + 8);
        } else {
            const float* ap = (const float*)Ap + (row0 + srow) * (long)K + sk;
            floatx4 f0 = *(const floatx4*)ap,       f1 = *(const floatx4*)(ap + 4),
                    f2 = *(const floatx4*)(ap + 8), f3 = *(const floatx4*)(ap + 12);
#pragma unroll
            for (int e = 0; e < 4; ++e) {
                a0[e] = f2bf(f0[e]); a0[e + 4] = f2bf(f1[e]);
                a1[e] = f2bf(f2[e]); a1[e + 4] = f2bf(f3[e]);
            }
        }
        short8* As8 = (short8*)As;
        const int u0 = sk >> 3, sw = (srow >> 1) & 3;
        As8[srow * 4 + ((u0)     ^ sw)] = a0;
        As8[srow * 4 + ((u0 + 1) ^ sw)] = a1;
    }
    __syncthreads();

    int buf = 0;
    for (int kt = 0; kt < K; kt += 32) {
        const bool nlast = (kt + 32 < K);
        floatx4 f0, f1, f2, f3;
        short8 s0, s1;
        if (nlast) {
            // issue next-tile loads early
            char* d0 = (char*)Bs + (buf ^ 1) * 8192 + wid * 1024;
            gld16(bsrc + kt + 32, d0);
            gld16(bsrc + 64L * K + kt + 32, d0 + 4096);
            if constexpr (ABF) {
                const short* ap = (const short*)Ap + (row0 + srow) * (long)K + kt + 32 + sk;
                s0 = *(const short8*)ap; s1 = *(const short8*)(ap + 8);
            } else {
                const float* ap = (const float*)Ap + (row0 + srow) * (long)K + kt + 32 + sk;
                f0 = *(const floatx4*)ap;       f1 = *(const floatx4*)(ap + 4);
                f2 = *(const floatx4*)(ap + 8); f3 = *(const floatx4*)(ap + 12);
            }
        }
        // frags + MFMA on current buffer
        short8* As8 = (short8*)((char*)As + buf * 8192);
        short8* Bs8 = (short8*)((char*)Bs + buf * 8192);
        short8 af[4], bfq[4];
#pragma unroll
        for (int fm = 0; fm < 4; ++fm) {
            const int r = wr * 64 + fm * 16 + c;
            af[fm] = As8[r * 4 + (g ^ ((r >> 1) & 3))];
        }
#pragma unroll
        for (int fn = 0; fn < 4; ++fn) {
            const int cc = wc * 64 + fn * 16 + c;
            bfq[fn] = Bs8[cc * 4 + (g ^ ((cc >> 1) & 3))];
        }
#pragma unroll
        for (int fm = 0; fm < 4; ++fm)
#pragma unroll
            for (int fn = 0; fn < 4; ++fn)
                acc[fm][fn] = __builtin_amdgcn_mfma_f32_16x16x32_bf16(af[fm], bfq[fn], acc[fm][fn], 0, 0, 0);
        // write next A tile (cvt late)
        if (nlast) {
            short8 a0, a1;
            if constexpr (ABF) { a0 = s0; a1 = s1; }
            else {
#pragma unroll
                for (int e = 0; e < 4; ++e) {
                    a0[e] = f2bf(f0[e]); a0[e + 4] = f2bf(f1[e]);
                    a1[e] = f2bf(f2[e]); a1[e + 4] = f2bf(f3[e]);
                }
            }
            short8* An8 = (short8*)((char*)As + (buf ^ 1) * 8192);
            const int u0 = sk >> 3, sw = (srow >> 1) & 3;
            An8[srow * 4 + ((u0)     ^ sw)] = a0;
            An8[srow * 4 + ((u0 + 1) ^ sw)] = a1;
        }
        __syncthreads();
        buf ^= 1;
    }

    // epilogue
    const float sc = gb.scale[z];
    const float* bp = gb.bias[z];
    const int om = gb.omode[z];
    void* Cp = gb.C[z];
#pragma unroll
    for (int fn = 0; fn < 4; ++fn) {
        const int ccol = col0 + wc * 64 + fn * 16 + c;
        const float bv = bp[ccol];
#pragma unroll
        for (int fm = 0; fm < 4; ++fm) {
            const long r0 = row0 + wr * 64 + fm * 16 + g * 4;
#pragma unroll
            for (int reg = 0; reg < 4; ++reg) {
                const float val = (acc[fm][fn][reg] + bv) * sc;
                const long rr = r0 + reg;
                if (om == 0) {
                    ((short*)Cp)[rr * Dq + ccol] = f2bf(val);
                } else if (om == 1) {
                    const long idx = ((long)(rr >> 11) * Dq + ccol) * (long)Mq + (rr & (Mq - 1));
                    ((short*)Cp)[idx] = f2bf(val);
                } else {
                    ((float*)Cp)[rr * Dq + ccol] = val;
                }
            }
        }
    }
}

// ---------------------------------------------------------------------------
// Fused flash attention, swapped-operand 32x32, exp2 domain.
// Grid 1024 = (qt 0..15)*(bh 0..63); block 256 = 4 waves, wave = 32 q-rows.
// Double-buffered K/V staging (one barrier per tile).
// ---------------------------------------------------------------------------
__global__ __launch_bounds__(256, 4)
void attn_fused(const short* __restrict__ qg_, const short* __restrict__ kg_,
                const short* __restrict__ vtg, const short* __restrict__ bmg,
                short* __restrict__ outg)
{
    __shared__ __align__(16) short k_lds[2][64 * 64];   // 2 x 8KB
    __shared__ __align__(16) short v_lds[2][64 * 64];   // 2 x 8KB

    const int tid = threadIdx.x;
    const int lane = tid & 63;
    const int w = tid >> 6;          // 0..3
    const int hi = lane >> 5;
    const int q31 = lane & 31;

    // bh = blk&63 -> blk%8 = bh%8: all 16 qt-blocks of one (b,h) on one XCD.
    const int blk = blockIdx.x;
    const int bh = blk & 63;
    const int qt = blk >> 6;         // 0..15
    const int b = bh >> 4, h = bh & 15;

    const long qbase = (long)b * Nq + qt * 128 + w * 32;   // + q31

    short8 qf[4];
#pragma unroll
    for (int ks = 0; ks < 4; ++ks)
        qf[ks] = *(const short8*)(qg_ + (qbase + q31) * Dq + h * 64 + ks * 16 + hi * 8);

    floatx16 oa[2];
    oa[0] = (floatx16)0.0f; oa[1] = (floatx16)0.0f;
    float m_s = -1e37f, l_s = 0.0f;

    // staging: issue i covers rows i*32 + (tid>>3); stored unit tid&7,
    // source unit su = (tid&7) ^ (row&7)  (invariant across issues: i*32%8==0)
    const int sr = tid >> 3;                       // 0..31
    const int su = (tid & 7) ^ (sr & 7);
    const char* ksrc = (const char*)(kg_ + ((long)b * Mq + sr) * Dq + h * 64 + su * 8);
    const char* vsrc = (const char*)(vtg + ((long)b * Dq + h * 64 + sr) * Mq + su * 8);

#define STAGE(bf, kt2) do {                                                   \
        const long j0b = (long)(kt2) * 64;                                    \
        char* kd = (char*)k_lds + (bf) * 8192 + w * 1024;                     \
        char* vd = (char*)v_lds + (bf) * 8192 + w * 1024;                     \
        gld16(ksrc + j0b * (Dq * 2), kd);                                     \
        gld16(ksrc + (j0b + 32) * (Dq * 2), kd + 4096);                       \
        gld16(vsrc + j0b * 2, vd);                                            \
        gld16(vsrc + 32L * Mq * 2 + j0b * 2, vd + 4096);                      \
    } while (0)

    STAGE(0, 0);
    __syncthreads();

    int buf = 0;
    for (int kt = 0; kt < 32; ++kt) {
        if (kt < 31) STAGE(buf ^ 1, kt + 1);
        // bias loads for THIS tile, issued before QK^T (latency covered by MFMA)
        const short* brow = bmg + (qbase + q31) * Mq + (long)kt * 64;
        short4v bb[8];
#pragma unroll
        for (int kg = 0; kg < 2; ++kg)
#pragma unroll
            for (int Qh = 0; Qh < 4; ++Qh)
                bb[kg * 4 + Qh] = *(const short4v*)(brow + kg * 32 + Qh * 8 + hi * 4);

        const char* kb = (const char*)k_lds + buf * 8192;
        const char* vb = (const char*)v_lds + buf * 8192;

        // QK^T (K frags scoped per kg to cap VGPR)
        floatx16 sa[2];
#pragma unroll
        for (int kg = 0; kg < 2; ++kg) {
            short8 kf[4];
#pragma unroll
            for (int ks = 0; ks < 4; ++ks) {
                const int r = kg * 32 + q31;
                const int up = (2 * ks + hi) ^ (r & 7);
                kf[ks] = *(const short8*)(kb + r * 128 + up * 16);
            }
            sa[kg] = (floatx16)0.0f;
#pragma unroll
            for (int ks = 0; ks < 4; ++ks)
                sa[kg] = __builtin_amdgcn_mfma_f32_32x32x16_bf16(kf[ks], qf[ks], sa[kg], 0, 0, 0);
        }

        // logits (exp2 domain) + online softmax
        float p[32];
#pragma unroll
        for (int kg = 0; kg < 2; ++kg)
#pragma unroll
            for (int Qh = 0; Qh < 4; ++Qh) {
                const short4v bv4 = bb[kg * 4 + Qh];
#pragma unroll
                for (int e = 0; e < 4; ++e)
                    p[kg * 16 + Qh * 4 + e] = sa[kg][Qh * 4 + e] + bf2f(bv4[e]);
            }
        float t16[16];
#pragma unroll
        for (int i = 0; i < 16; ++i) t16[i] = fmaxf(p[2 * i], p[2 * i + 1]);
#pragma unroll
        for (int i = 0; i < 8; ++i) t16[i] = fmaxf(t16[2 * i], t16[2 * i + 1]);
        t16[0] = fmaxf(fmaxf(fmaxf(t16[0], t16[1]), fmaxf(t16[2], t16[3])),
                       fmaxf(fmaxf(t16[4], t16[5]), fmaxf(t16[6], t16[7])));
        const float pm = fmaxf(t16[0], __shfl_xor(t16[0], 32));
        if (!__all(pm <= m_s + 11.5f)) {            // defer-max, 8 nats in exp2 units
            const float mn = fmaxf(m_s, pm);
            const float al = exp2_fast(m_s - mn);
            l_s *= al;
            oa[0] *= al; oa[1] *= al;
            m_s = mn;
        }
#pragma unroll
        for (int i = 0; i < 32; ++i) p[i] = exp2_fast(p[i] - m_s);
        float s16[16];
#pragma unroll
        for (int i = 0; i < 16; ++i) s16[i] = p[2 * i] + p[2 * i + 1];
#pragma unroll
        for (int i = 0; i < 8; ++i) s16[i] = s16[2 * i] + s16[2 * i + 1];
        float rs = ((s16[0] + s16[1]) + (s16[2] + s16[3])) +
                   ((s16[4] + s16[5]) + (s16[6] + s16[7]));
        rs += __shfl_xor(rs, 32);
        l_s += rs;

        // pack P -> PV B-frags (cvt_pk + permlane32_swap)
        uint4v pw[4];
#pragma unroll
        for (int kg = 0; kg < 2; ++kg) {
            unsigned w0 = cvtpk_bf16(p[kg * 16 + 0], p[kg * 16 + 1]);
            unsigned w1 = cvtpk_bf16(p[kg * 16 + 2], p[kg * 16 + 3]);
            unsigned w2 = cvtpk_bf16(p[kg * 16 + 4], p[kg * 16 + 5]);
            unsigned w3 = cvtpk_bf16(p[kg * 16 + 6], p[kg * 16 + 7]);
            swap32(w0, w2); swap32(w1, w3);
            pw[kg * 2][0] = w0; pw[kg * 2][1] = w1; pw[kg * 2][2] = w2; pw[kg * 2][3] = w3;
            unsigned w4 = cvtpk_bf16(p[kg * 16 + 8],  p[kg * 16 + 9]);
            unsigned w5 = cvtpk_bf16(p[kg * 16 + 10], p[kg * 16 + 11]);
            unsigned w6 = cvtpk_bf16(p[kg * 16 + 12], p[kg * 16 + 13]);
            unsigned w7 = cvtpk_bf16(p[kg * 16 + 14], p[kg * 16 + 15]);
            swap32(w4, w6); swap32(w5, w7);
            pw[kg * 2 + 1][0] = w4; pw[kg * 2 + 1][1] = w5; pw[kg * 2 + 1][2] = w6; pw[kg * 2 + 1][3] = w7;
        }

        // PV (V frags scoped per dg)
#pragma unroll
        for (int dg = 0; dg < 2; ++dg) {
            short8 vf[4];
#pragma unroll
            for (int ks = 0; ks < 4; ++ks) {
                const int r = dg * 32 + q31;
                const int up = (2 * ks + hi) ^ (r & 7);
                vf[ks] = *(const short8*)(vb + r * 128 + up * 16);
            }
#pragma unroll
            for (int ks = 0; ks < 4; ++ks)
                oa[dg] = __builtin_amdgcn_mfma_f32_32x32x16_bf16(
                    vf[ks], __builtin_bit_cast(short8, pw[ks]), oa[dg], 0, 0, 0);
        }
        __syncthreads();
        buf ^= 1;
    }
#undef STAGE

    const float invl = 1.0f / l_s;
    short* op = outg + (qbase + q31) * Dq + h * 64;
#pragma unroll
    for (int dg = 0; dg < 2; ++dg)
#pragma unroll
        for (int Qh = 0; Qh < 4; ++Qh) {
            short4v t;
#pragma unroll
            for (int e = 0; e < 4; ++e)
                t[e] = f2bf(oa[dg][Qh * 4 + e] * invl);
            *(short4v*)(op + dg * 32 + Qh * 8 + hi * 4) = t;
        }
}

// ---------------------------------------------------------------------------
extern "C" void kernel_launch(void* const* d_in, const int* in_sizes, int n_in,
                              void* d_out, int out_size, void* d_ws, size_t ws_size,
                              hipStream_t stream)
{
    const float* Q    = (const float*)d_in[0];
    const float* K    = (const float*)d_in[1];
    const float* V    = (const float*)d_in[2];
    const float* bias = (const float*)d_in[3];
    const int*   mask = (const int*)d_in[4];
    const float* Wq   = (const float*)d_in[5];
    const float* bq   = (const float*)d_in[6];
    const float* Wk   = (const float*)d_in[7];
    const float* bk   = (const float*)d_in[8];
    const float* Wv   = (const float*)d_in[9];
    const float* bv   = (const float*)d_in[10];
    const float* Wo   = (const float*)d_in[11];
    const float* bo   = (const float*)d_in[12];

    // ws (shorts): q|k|vT|a (8.39M each) | bm (16.78M) | Wb (4x1.05M) = 109 MB
    const size_t TSZ = (size_t)Bq * Nq * Dq;       // 8,388,608
    short* q_ws  = (short*)d_ws;
    short* k_ws  = q_ws  + TSZ;
    short* vt_ws = k_ws  + TSZ;
    short* a_ws  = vt_ws + TSZ;
    short* bm_ws = a_ws  + TSZ;
    short* w_ws  = bm_ws + (size_t)Bq * Nq * Mq;
    (void)ws_size;

    bias_prep<<<dim3(8192), dim3(256), 0, stream>>>(bias, mask, bm_ws);
    cvt_w<<<dim3(512, 4), dim3(256), 0, stream>>>(Wq, Wk, Wv, Wo, w_ws);

    GB g1{};
    g1.A[0] = Q;  g1.A[1] = K;  g1.A[2] = V;
    g1.W[0] = w_ws; g1.W[1] = w_ws + Dq * Dq; g1.W[2] = w_ws + 2 * Dq * Dq;
    g1.bias[0] = bq; g1.bias[1] = bk; g1.bias[2] = bv;
    g1.C[0] = q_ws; g1.C[1] = k_ws; g1.C[2] = vt_ws;
    g1.scale[0] = 0.125f * 1.44269504f; g1.scale[1] = 1.0f; g1.scale[2] = 1.0f;
    g1.omode[0] = 0; g1.omode[1] = 0; g1.omode[2] = 1;
    gemm_bt<false><<<dim3(64, 8, 3), dim3(256), 0, stream>>>(g1, Dq);

    attn_fused<<<dim3(1024), dim3(256), 0, stream>>>(q_ws, k_ws, vt_ws, bm_ws, a_ws);

    GB g2{};
    g2.A[0] = a_ws;
    g2.W[0] = w_ws + 3 * Dq * Dq;
    g2.bias[0] = bo;
    g2.C[0] = d_out;
    g2.scale[0] = 1.0f;
    g2.omode[0] = 2;
    gemm_bt<true><<<dim3(64, 8, 1), dim3(256), 0, stream>>>(g2, Dq);
}

// Round 5
// 328.323 us; speedup vs baseline: 2.8705x; 1.0427x over previous
//
#include <hip/hip_runtime.h>
#include <hip/hip_bf16.h>

// Problem constants
#define Bq 4
#define Nq 2048
#define Mq 2048
#define Dq 1024
#define Hq 16
// HD = 64; logits in exp2 domain: scale 0.125*log2e folded into Q GEMM,
// log2e folded into bias prepass. Defer-max online softmax (R3-proven).

typedef __attribute__((ext_vector_type(8))) short short8;
typedef __attribute__((ext_vector_type(4))) short short4v;
typedef __attribute__((ext_vector_type(4))) float floatx4;
typedef __attribute__((ext_vector_type(16))) float floatx16;
typedef __attribute__((ext_vector_type(4))) unsigned uint4v;

static __device__ __forceinline__ short f2bf(float f) {
    __hip_bfloat16 h = __float2bfloat16(f);   // RNE
    short r;
    __builtin_memcpy(&r, &h, 2);
    return r;
}
static __device__ __forceinline__ float bf2f(short s) {
    unsigned u = ((unsigned)(unsigned short)s) << 16;
    float f;
    __builtin_memcpy(&f, &u, 4);
    return f;
}
static __device__ __forceinline__ unsigned cvtpk_bf16(float lo, float hi) {
    unsigned r;
    asm("v_cvt_pk_bf16_f32 %0, %1, %2" : "=v"(r) : "v"(lo), "v"(hi));
    return r;
}
static __device__ __forceinline__ void swap32(unsigned &a, unsigned &b) {
    asm("v_permlane32_swap_b32 %0, %1" : "+v"(a), "+v"(b));
}
static __device__ __forceinline__ float exp2_fast(float x) {
    float r;
    asm("v_exp_f32 %0, %1" : "=v"(r) : "v"(x));   // D = 2^S0
    return r;
}
static __device__ __forceinline__ void gld16(const void* g, void* l) {
    __builtin_amdgcn_global_load_lds(
        (const __attribute__((address_space(1))) unsigned int*)g,
        (__attribute__((address_space(3))) unsigned int*)l, 16, 0, 0);
}

// ---------------------------------------------------------------------------
// bias prepass: bm[b][n][m] = bf16(mask ? -1e38 : bias*log2e)
// Launched AFTER the QKV GEMM (bm region overlaps kin/vin scratch).
// ---------------------------------------------------------------------------
__global__ void bias_prep(const float* __restrict__ bias, const int* __restrict__ mask,
                          short* __restrict__ out)
{
    const long i = ((long)blockIdx.x * 256 + threadIdx.x) * 8;
    const int m = (int)(i & (Mq - 1));
    const int b = (int)(i >> 22);           // i / (2048*2048)
    floatx4 f0 = *(const floatx4*)(bias + i);
    floatx4 f1 = *(const floatx4*)(bias + i + 4);
    const int* mp = mask + b * Mq + m;
    short8 o;
#pragma unroll
    for (int e = 0; e < 4; ++e) {
        o[e]     = mp[e]     ? f2bf(-1e38f) : f2bf(f0[e] * 1.44269504f);
        o[e + 4] = mp[e + 4] ? f2bf(-1e38f) : f2bf(f1[e] * 1.44269504f);
    }
    *(short8*)(out + i) = o;
}

// ---------------------------------------------------------------------------
// f32 -> bf16 bulk convert via RNE f2bf (1024x1024 weights or activations)
// ---------------------------------------------------------------------------
__global__ void cvt_bf(const float* __restrict__ s0, const float* __restrict__ s1,
                       const float* __restrict__ s2, const float* __restrict__ s3,
                       short* __restrict__ out, long per)
{
    const int z = blockIdx.y;
    const float* s = (z == 0) ? s0 : (z == 1) ? s1 : (z == 2) ? s2 : s3;
    short* d = out + (long)z * per;
    const long i = ((long)blockIdx.x * 256 + threadIdx.x) * 8;
    floatx4 f0 = *(const floatx4*)(s + i);
    floatx4 f1 = *(const floatx4*)(s + i + 4);
    short8 o;
#pragma unroll
    for (int e = 0; e < 4; ++e) { o[e] = f2bf(f0[e]); o[e + 4] = f2bf(f1[e]); }
    *(short8*)(d + i) = o;
}

// ---------------------------------------------------------------------------
// Batched GEMM (all-bf16 operands): C[r][c] = (sum_k A[r][k]*W[c][k] + bias[c])*scale
// A: 8192 x K bf16, W: 1024 x K bf16. 128x128 tile, 4 waves, BK=32, LDS dbuf,
// both operands staged via global_load_lds w=16 with pre-swizzled source.
// omode: 0 bf16 [r][c], 1 bf16 transposed-per-batch [b][c][m], 2 f32 [r][c].
// ---------------------------------------------------------------------------
struct GB {
    const short* A[3];
    const short* W[3];
    const float* bias[3];
    void* C[3];
    float scale[3];
    int omode[3];
};

__global__ __launch_bounds__(256, 3)
void gemm_all(GB gb, int K)
{
    __shared__ __align__(16) short As[2][128 * 32];
    __shared__ __align__(16) short Bs[2][128 * 32];

    const int z = blockIdx.z;
    const short* Ap = gb.A[z];
    const short* Wp = gb.W[z];

    const int tid = threadIdx.x;
    const int lane = tid & 63;
    const int wid = tid >> 6;
    const int wr = wid >> 1, wc = wid & 1;
    const int g = lane >> 4, c = lane & 15;
    const long row0 = (long)blockIdx.x * 128;
    const int col0 = blockIdx.y * 128;

    // gld staging: thread covers rows R0 = tid>>2 (+64 for 2nd issue);
    // stored unit u' = tid&3, source unit = u' ^ ((R0>>1)&3)
    // (swizzle-invariant across issues: (64+R0)>>1 & 3 == (R0>>1)&3 since 32&3==0)
    const int R0 = tid >> 2;
    const int ub = (tid & 3) ^ ((R0 >> 1) & 3);
    const short* asrc = Ap + (row0 + R0) * (long)K + ub * 8;
    const short* bsrc = Wp + ((long)col0 + R0) * K + ub * 8;

    floatx4 acc[4][4];
#pragma unroll
    for (int i = 0; i < 4; ++i)
#pragma unroll
        for (int j = 0; j < 4; ++j) acc[i][j] = (floatx4)0.0f;

#define GSTAGE(buf, koff) do {                                                \
        char* ad = (char*)As + (buf) * 8192 + wid * 1024;                     \
        char* bd = (char*)Bs + (buf) * 8192 + wid * 1024;                     \
        gld16(asrc + (koff), ad);                                             \
        gld16(asrc + 64L * K + (koff), ad + 4096);                            \
        gld16(bsrc + (koff), bd);                                             \
        gld16(bsrc + 64L * K + (koff), bd + 4096);                            \
    } while (0)

    GSTAGE(0, 0);
    __syncthreads();

    int buf = 0;
    for (int kt = 0; kt < K; kt += 32) {
        if (kt + 32 < K) GSTAGE(buf ^ 1, kt + 32);
        short8* As8 = (short8*)((char*)As + buf * 8192);
        short8* Bs8 = (short8*)((char*)Bs + buf * 8192);
        short8 af[4], bfq[4];
#pragma unroll
        for (int fm = 0; fm < 4; ++fm) {
            const int r = wr * 64 + fm * 16 + c;
            af[fm] = As8[r * 4 + (g ^ ((r >> 1) & 3))];
        }
#pragma unroll
        for (int fn = 0; fn < 4; ++fn) {
            const int cc = wc * 64 + fn * 16 + c;
            bfq[fn] = Bs8[cc * 4 + (g ^ ((cc >> 1) & 3))];
        }
#pragma unroll
        for (int fm = 0; fm < 4; ++fm)
#pragma unroll
            for (int fn = 0; fn < 4; ++fn)
                acc[fm][fn] = __builtin_amdgcn_mfma_f32_16x16x32_bf16(af[fm], bfq[fn], acc[fm][fn], 0, 0, 0);
        __syncthreads();
        buf ^= 1;
    }
#undef GSTAGE

    // epilogue
    const float sc = gb.scale[z];
    const float* bp = gb.bias[z];
    const int om = gb.omode[z];
    void* Cp = gb.C[z];
#pragma unroll
    for (int fn = 0; fn < 4; ++fn) {
        const int ccol = col0 + wc * 64 + fn * 16 + c;
        const float bv = bp[ccol];
#pragma unroll
        for (int fm = 0; fm < 4; ++fm) {
            const long r0 = row0 + wr * 64 + fm * 16 + g * 4;
#pragma unroll
            for (int reg = 0; reg < 4; ++reg) {
                const float val = (acc[fm][fn][reg] + bv) * sc;
                const long rr = r0 + reg;
                if (om == 0) {
                    ((short*)Cp)[rr * Dq + ccol] = f2bf(val);
                } else if (om == 1) {
                    const long idx = ((long)(rr >> 11) * Dq + ccol) * (long)Mq + (rr & (Mq - 1));
                    ((short*)Cp)[idx] = f2bf(val);
                } else {
                    ((float*)Cp)[rr * Dq + ccol] = val;
                }
            }
        }
    }
}

// ---------------------------------------------------------------------------
// Fused flash attention, swapped-operand 32x32, exp2 domain, defer-max (R3).
// Grid 1024 = (qt 0..15)*(bh 0..63); block 256 = 4 waves, wave = 32 q-rows.
// QK^T accumulator initialized with bias (C-in, f32-equivalent to post-add).
// ---------------------------------------------------------------------------
__global__ __launch_bounds__(256, 4)
void attn_fused(const short* __restrict__ qg_, const short* __restrict__ kg_,
                const short* __restrict__ vtg, const short* __restrict__ bmg,
                short* __restrict__ outg)
{
    __shared__ __align__(16) short k_lds[2][64 * 64];   // 2 x 8KB
    __shared__ __align__(16) short v_lds[2][64 * 64];   // 2 x 8KB

    const int tid = threadIdx.x;
    const int lane = tid & 63;
    const int w = tid >> 6;          // 0..3
    const int hi = lane >> 5;
    const int q31 = lane & 31;

    // bh = blk&63 -> blk%8 = bh%8: all 16 qt-blocks of one (b,h) on one XCD.
    const int blk = blockIdx.x;
    const int bh = blk & 63;
    const int qt = blk >> 6;         // 0..15
    const int b = bh >> 4, h = bh & 15;

    const long qbase = (long)b * Nq + qt * 128 + w * 32;   // + q31

    short8 qf[4];
#pragma unroll
    for (int ks = 0; ks < 4; ++ks)
        qf[ks] = *(const short8*)(qg_ + (qbase + q31) * Dq + h * 64 + ks * 16 + hi * 8);

    floatx16 oa[2];
    oa[0] = (floatx16)0.0f; oa[1] = (floatx16)0.0f;
    float m_s = -1e37f, l_s = 0.0f;

    // staging: source unit su = (tid&7) ^ (row&7), row = tid>>3
    const int sr = tid >> 3;                       // 0..31
    const int su = (tid & 7) ^ (sr & 7);
    const char* ksrc = (const char*)(kg_ + ((long)b * Mq + sr) * Dq + h * 64 + su * 8);
    const char* vsrc = (const char*)(vtg + ((long)b * Dq + h * 64 + sr) * Mq + su * 8);

#define STAGE(bf, kt2) do {                                                   \
        const long j0b = (long)(kt2) * 64;                                    \
        char* kd = (char*)k_lds + (bf) * 8192 + w * 1024;                     \
        char* vd = (char*)v_lds + (bf) * 8192 + w * 1024;                     \
        gld16(ksrc + j0b * (Dq * 2), kd);                                     \
        gld16(ksrc + (j0b + 32) * (Dq * 2), kd + 4096);                       \
        gld16(vsrc + j0b * 2, vd);                                            \
        gld16(vsrc + 32L * Mq * 2 + j0b * 2, vd + 4096);                      \
    } while (0)

    STAGE(0, 0);
    __syncthreads();

    int buf = 0;
    for (int kt = 0; kt < 32; ++kt) {
        if (kt < 31) STAGE(buf ^ 1, kt + 1);
        // bias loads for THIS tile (feed the MFMA C-init)
        const short* brow = bmg + (qbase + q31) * Mq + (long)kt * 64;
        short4v bb[8];
#pragma unroll
        for (int kg = 0; kg < 2; ++kg)
#pragma unroll
            for (int Qh = 0; Qh < 4; ++Qh)
                bb[kg * 4 + Qh] = *(const short4v*)(brow + kg * 32 + Qh * 8 + hi * 4);

        const char* kb = (const char*)k_lds + buf * 8192;
        const char* vb = (const char*)v_lds + buf * 8192;

        // C-init = bias, then QK^T accumulates on top -> sa = logit (log2 units)
        floatx16 sa[2];
#pragma unroll
        for (int kg = 0; kg < 2; ++kg)
#pragma unroll
            for (int Qh = 0; Qh < 4; ++Qh) {
                const short4v b4 = bb[kg * 4 + Qh];
#pragma unroll
                for (int e = 0; e < 4; ++e)
                    sa[kg][Qh * 4 + e] = bf2f(b4[e]);
            }
#pragma unroll
        for (int kg = 0; kg < 2; ++kg) {
            short8 kf[4];
#pragma unroll
            for (int ks = 0; ks < 4; ++ks) {
                const int r = kg * 32 + q31;
                const int up = (2 * ks + hi) ^ (r & 7);
                kf[ks] = *(const short8*)(kb + r * 128 + up * 16);
            }
#pragma unroll
            for (int ks = 0; ks < 4; ++ks)
                sa[kg] = __builtin_amdgcn_mfma_f32_32x32x16_bf16(kf[ks], qf[ks], sa[kg], 0, 0, 0);
        }

        // online softmax with defer-max (R3-proven)
        float p[32];
#pragma unroll
        for (int kg = 0; kg < 2; ++kg)
#pragma unroll
            for (int j = 0; j < 16; ++j)
                p[kg * 16 + j] = sa[kg][j];
        float t16[16];
#pragma unroll
        for (int i = 0; i < 16; ++i) t16[i] = fmaxf(p[2 * i], p[2 * i + 1]);
#pragma unroll
        for (int i = 0; i < 8; ++i) t16[i] = fmaxf(t16[2 * i], t16[2 * i + 1]);
        t16[0] = fmaxf(fmaxf(fmaxf(t16[0], t16[1]), fmaxf(t16[2], t16[3])),
                       fmaxf(fmaxf(t16[4], t16[5]), fmaxf(t16[6], t16[7])));
        const float pm = fmaxf(t16[0], __shfl_xor(t16[0], 32));
        if (!__all(pm <= m_s + 11.5f)) {            // defer-max, 8 nats in exp2 units
            const float mn = fmaxf(m_s, pm);
            const float al = exp2_fast(m_s - mn);
            l_s *= al;
            oa[0] *= al; oa[1] *= al;
            m_s = mn;
        }
#pragma unroll
        for (int i = 0; i < 32; ++i) p[i] = exp2_fast(p[i] - m_s);
        float s16[16];
#pragma unroll
        for (int i = 0; i < 16; ++i) s16[i] = p[2 * i] + p[2 * i + 1];
#pragma unroll
        for (int i = 0; i < 8; ++i) s16[i] = s16[2 * i] + s16[2 * i + 1];
        float rs = ((s16[0] + s16[1]) + (s16[2] + s16[3])) +
                   ((s16[4] + s16[5]) + (s16[6] + s16[7]));
        rs += __shfl_xor(rs, 32);
        l_s += rs;

        // pack P -> PV B-frags (cvt_pk + permlane32_swap)
        uint4v pw[4];
#pragma unroll
        for (int kg = 0; kg < 2; ++kg) {
            unsigned w0 = cvtpk_bf16(p[kg * 16 + 0], p[kg * 16 + 1]);
            unsigned w1 = cvtpk_bf16(p[kg * 16 + 2], p[kg * 16 + 3]);
            unsigned w2 = cvtpk_bf16(p[kg * 16 + 4], p[kg * 16 + 5]);
            unsigned w3 = cvtpk_bf16(p[kg * 16 + 6], p[kg * 16 + 7]);
            swap32(w0, w2); swap32(w1, w3);
            pw[kg * 2][0] = w0; pw[kg * 2][1] = w1; pw[kg * 2][2] = w2; pw[kg * 2][3] = w3;
            unsigned w4 = cvtpk_bf16(p[kg * 16 + 8],  p[kg * 16 + 9]);
            unsigned w5 = cvtpk_bf16(p[kg * 16 + 10], p[kg * 16 + 11]);
            unsigned w6 = cvtpk_bf16(p[kg * 16 + 12], p[kg * 16 + 13]);
            unsigned w7 = cvtpk_bf16(p[kg * 16 + 14], p[kg * 16 + 15]);
            swap32(w4, w6); swap32(w5, w7);
            pw[kg * 2 + 1][0] = w4; pw[kg * 2 + 1][1] = w5; pw[kg * 2 + 1][2] = w6; pw[kg * 2 + 1][3] = w7;
        }

        // PV (V frags scoped per dg)
#pragma unroll
        for (int dg = 0; dg < 2; ++dg) {
            short8 vf[4];
#pragma unroll
            for (int ks = 0; ks < 4; ++ks) {
                const int r = dg * 32 + q31;
                const int up = (2 * ks + hi) ^ (r & 7);
                vf[ks] = *(const short8*)(vb + r * 128 + up * 16);
            }
#pragma unroll
            for (int ks = 0; ks < 4; ++ks)
                oa[dg] = __builtin_amdgcn_mfma_f32_32x32x16_bf16(
                    vf[ks], __builtin_bit_cast(short8, pw[ks]), oa[dg], 0, 0, 0);
        }
        __syncthreads();
        buf ^= 1;
    }
#undef STAGE

    const float invl = 1.0f / l_s;
    short* op = outg + (qbase + q31) * Dq + h * 64;
#pragma unroll
    for (int dg = 0; dg < 2; ++dg)
#pragma unroll
        for (int Qh = 0; Qh < 4; ++Qh) {
            short4v t;
#pragma unroll
            for (int e = 0; e < 4; ++e)
                t[e] = f2bf(oa[dg][Qh * 4 + e] * invl);
            *(short4v*)(op + dg * 32 + Qh * 8 + hi * 4) = t;
        }
}

// ---------------------------------------------------------------------------
extern "C" void kernel_launch(void* const* d_in, const int* in_sizes, int n_in,
                              void* d_out, int out_size, void* d_ws, size_t ws_size,
                              hipStream_t stream)
{
    const float* Q    = (const float*)d_in[0];
    const float* K    = (const float*)d_in[1];
    const float* V    = (const float*)d_in[2];
    const float* bias = (const float*)d_in[3];
    const int*   mask = (const int*)d_in[4];
    const float* Wq   = (const float*)d_in[5];
    const float* bq   = (const float*)d_in[6];
    const float* Wk   = (const float*)d_in[7];
    const float* bk   = (const float*)d_in[8];
    const float* Wv   = (const float*)d_in[9];
    const float* bv   = (const float*)d_in[10];
    const float* Wo   = (const float*)d_in[11];
    const float* bo   = (const float*)d_in[12];

    // ws layout (shorts), 109 MB total (== R3's proven footprint):
    //   [0]    q_ws    (TSZ)
    //   [1TSZ] k_ws    (TSZ)
    //   [2TSZ] vt_ws   (TSZ)
    //   [3TSZ] a_ws    (TSZ)   <- doubles as qin before attention
    //   [4TSZ] bm_ws   (2TSZ)  <- doubles as kin/vin before bias_prep
    //   [6TSZ] w_ws    (4*Dq*Dq)
    const size_t TSZ = (size_t)Bq * Nq * Dq;       // 8,388,608
    short* q_ws  = (short*)d_ws;
    short* k_ws  = q_ws  + TSZ;
    short* vt_ws = k_ws  + TSZ;
    short* a_ws  = vt_ws + TSZ;        // qin lives here first
    short* bm_ws = a_ws  + TSZ;        // kin, vin live here first
    short* w_ws  = bm_ws + 2 * TSZ;
    short* qin_ws = a_ws;
    short* kin_ws = bm_ws;
    short* vin_ws = bm_ws + TSZ;
    (void)ws_size;

    // 1) convert weights + activations to bf16 (RNE)
    cvt_bf<<<dim3(512, 4), dim3(256), 0, stream>>>(Wq, Wk, Wv, Wo, w_ws, (long)Dq * Dq);
    cvt_bf<<<dim3(4096, 3), dim3(256), 0, stream>>>(Q, K, V, V, qin_ws, (long)TSZ);

    // 2) QKV projections (read qin/kin/vin, write q/k/vT)
    GB g1{};
    g1.A[0] = qin_ws; g1.A[1] = kin_ws; g1.A[2] = vin_ws;
    g1.W[0] = w_ws; g1.W[1] = w_ws + Dq * Dq; g1.W[2] = w_ws + 2 * Dq * Dq;
    g1.bias[0] = bq; g1.bias[1] = bk; g1.bias[2] = bv;
    g1.C[0] = q_ws; g1.C[1] = k_ws; g1.C[2] = vt_ws;
    g1.scale[0] = 0.125f * 1.44269504f; g1.scale[1] = 1.0f; g1.scale[2] = 1.0f;
    g1.omode[0] = 0; g1.omode[1] = 0; g1.omode[2] = 1;
    gemm_all<<<dim3(64, 8, 3), dim3(256), 0, stream>>>(g1, Dq);

    // 3) bias prepass (overwrites kin/vin region — QKV GEMM is done with it)
    bias_prep<<<dim3(8192), dim3(256), 0, stream>>>(bias, mask, bm_ws);

    // 4) fused attention (writes a_ws over qin — done being read)
    attn_fused<<<dim3(1024), dim3(256), 0, stream>>>(q_ws, k_ws, vt_ws, bm_ws, a_ws);

    // 5) output projection
    GB g2{};
    g2.A[0] = a_ws;
    g2.W[0] = w_ws + 3 * Dq * Dq;
    g2.bias[0] = bo;
    g2.C[0] = d_out;
    g2.scale[0] = 1.0f;
    g2.omode[0] = 2;
    gemm_all<<<dim3(64, 8, 1), dim3(256), 0, stream>>>(g2, Dq);
}